// Round 9
// baseline (180.345 us; speedup 1.0000x reference)
//
#include <hip/hip_runtime.h>

#define DDIM 256
#define HDIM 128
#define KLEN 1024
#define SCL 2.8853900817779268f   // 2*log2(e): exp2(SCL*x) == e^{2x}
#define WSTR 260                  // wt row stride; >=256 (no overlap!), mult of 4,
                                  // 260%32=4 -> 8 bank groups for stride-1 h rows

// ============ Projection -> Eq/Ek = exp2(SCL * in@W) ============
// Block = 64 rows x 64 h-half. Grid 544: 0..511 keys (XCD-swizzled), 512..543 queries.
// Full W half-tile staged TRANSPOSED in LDS (wt[h][d]) -> barrier-free K-loop.
// Thread owns h-pair (hg, hg+32): both reads hit 8 bank groups -> 4-way max.
__global__ __launch_bounds__(256) void proj_kernel(
    const float* __restrict__ queries, const float* __restrict__ keys,
    const float* __restrict__ W_q, const float* __restrict__ W_k,
    float* __restrict__ Eq, float* __restrict__ Ek)
{
    __shared__ union {
        float w[64 * WSTR];   // 65 KB: wt[h][d] = W[d][hbase+h]
        float t[64][68];      // keys transpose staging (epilogue only)
    } sm;

    int tid = threadIdx.x;
    int hg  = tid & 31;       // h index; owns hg and hg+32
    int rg  = tid >> 5;       // row-group (8 rows)
    int blk = blockIdx.x;

    const float* in; const float* W; int row0, hbase, b = 0, kc0 = 0; bool iskey;
    if (blk < 512) {
        iskey = true;
        int xcd = blk & 7, s = blk >> 3;
        b = ((s >= 32) ? 8 : 0) + xcd;
        int r = s & 31;
        kc0   = (r >> 1) * 64;
        hbase = (r & 1) << 6;
        row0  = b * KLEN + kc0;
        in = keys; W = W_k;
    } else {
        iskey = false;
        int qi = blk - 512;
        row0  = (qi >> 1) * 64;
        hbase = (qi & 1) << 6;
        in = queries; W = W_q;
    }

    // ---- stage W[0:256][hbase+0:64] -> wt[h][d] via 4x4 register transpose ----
    {
        int d4g = tid >> 4;            // 0..15
        int hl  = (tid & 15) << 2;     // 0..60
        #pragma unroll
        for (int i = 0; i < 4; i++) {
            int d = i * 64 + d4g * 4;
            float4 g0 = *(const float4*)(W + (size_t)(d + 0) * HDIM + hbase + hl);
            float4 g1 = *(const float4*)(W + (size_t)(d + 1) * HDIM + hbase + hl);
            float4 g2 = *(const float4*)(W + (size_t)(d + 2) * HDIM + hbase + hl);
            float4 g3 = *(const float4*)(W + (size_t)(d + 3) * HDIM + hbase + hl);
            *(float4*)(&sm.w[(hl + 0) * WSTR + d]) = make_float4(g0.x, g1.x, g2.x, g3.x);
            *(float4*)(&sm.w[(hl + 1) * WSTR + d]) = make_float4(g0.y, g1.y, g2.y, g3.y);
            *(float4*)(&sm.w[(hl + 2) * WSTR + d]) = make_float4(g0.z, g1.z, g2.z, g3.z);
            *(float4*)(&sm.w[(hl + 3) * WSTR + d]) = make_float4(g0.w, g1.w, g2.w, g3.w);
        }
    }
    __syncthreads();

    const float* r0p = in + (size_t)(row0 + rg * 8) * DDIM;
    const float* wp0 = &sm.w[(size_t)hg * WSTR];          // h = hbase+hg
    const float* wp1 = &sm.w[(size_t)(hg + 32) * WSTR];   // h = hbase+hg+32

    float2 acc[8];
    #pragma unroll
    for (int j = 0; j < 8; j++) acc[j] = make_float2(0.f, 0.f);

    #pragma unroll 4
    for (int d0 = 0; d0 < DDIM; d0 += 4) {
        float4 w0 = *(const float4*)(wp0 + d0);
        float4 w1 = *(const float4*)(wp1 + d0);
        #pragma unroll
        for (int j = 0; j < 8; j++) {
            float4 a = *(const float4*)(r0p + (size_t)j * DDIM + d0);
            acc[j].x = fmaf(a.x, w0.x, acc[j].x); acc[j].y = fmaf(a.x, w1.x, acc[j].y);
            acc[j].x = fmaf(a.y, w0.y, acc[j].x); acc[j].y = fmaf(a.y, w1.y, acc[j].y);
            acc[j].x = fmaf(a.z, w0.z, acc[j].x); acc[j].y = fmaf(a.z, w1.z, acc[j].y);
            acc[j].x = fmaf(a.w, w0.w, acc[j].x); acc[j].y = fmaf(a.w, w1.w, acc[j].y);
        }
    }

    if (!iskey) {
        #pragma unroll
        for (int j = 0; j < 8; j++) {
            float* er = Eq + (size_t)(row0 + rg * 8 + j) * HDIM + hbase;
            er[hg]      = __builtin_amdgcn_exp2f(SCL * acc[j].x);
            er[hg + 32] = __builtin_amdgcn_exp2f(SCL * acc[j].y);
        }
    } else {
        __syncthreads();   // done with sm.w
        #pragma unroll
        for (int j = 0; j < 8; j++) {
            int kl = rg * 8 + j;
            sm.t[hg][kl]      = __builtin_amdgcn_exp2f(SCL * acc[j].x);
            sm.t[hg + 32][kl] = __builtin_amdgcn_exp2f(SCL * acc[j].y);
        }
        __syncthreads();
        float* dst = Ek + (size_t)b * HDIM * KLEN + (size_t)hbase * KLEN + kc0;
        #pragma unroll
        for (int ii = 0; ii < 4; ii++) {
            int i2 = tid + 256 * ii;           // 1024 float4 slots: 64 h x 64 k
            int hh = i2 >> 4, c = (i2 & 15) << 2;
            float4 o = make_float4(sm.t[hh][c], sm.t[hh][c + 1],
                                   sm.t[hh][c + 2], sm.t[hh][c + 3]);
            *(float4*)(dst + (size_t)hh * KLEN + c) = o;
        }
    }
}

// ============ Scores + masked softmax ============
// Grid 512 (XCD-swizzled) = (b, q-pair). 256 threads, thread = 4 contiguous k x 2 q.
// Inner: 1 coalesced b128 Ek + 1 LDS b128 broadcast + 8 rcp + 8 fma per h.
__global__ __launch_bounds__(256) void score_kernel(
    const float* __restrict__ Eq, const float* __restrict__ Ek,
    const float* __restrict__ w_v, const int* __restrict__ valid_lens,
    float* __restrict__ p)
{
    __shared__ float4 eqw[HDIM];       // (eq0, eq1, -2*wv, 0)
    __shared__ float red0[4], red1[4];

    int tid = threadIdx.x, lane = tid & 63, wav = tid >> 6;
    int blk = blockIdx.x;
    int xcd = blk & 7, s = blk >> 3;
    int b = ((s >= 32) ? 8 : 0) + xcd;
    int qp = s & 31;
    int bq0 = b * 64 + qp * 2;
    int vlen = valid_lens[b];

    if (tid < HDIM)
        eqw[tid] = make_float4(Eq[(size_t)bq0 * HDIM + tid],
                               Eq[(size_t)(bq0 + 1) * HDIM + tid],
                               -2.0f * w_v[tid], 0.f);
    __syncthreads();

    int k0 = tid << 2;
    float a[8];
    #pragma unroll
    for (int i = 0; i < 8; i++) a[i] = 0.f;

    if (k0 < vlen) {
        const float* ekp = Ek + (size_t)b * HDIM * KLEN + k0;
        #pragma unroll 16
        for (int h = 0; h < HDIM; h++) {
            float4 ek = *(const float4*)(ekp + (size_t)h * KLEN);
            float4 e  = eqw[h];
            a[0] = fmaf(e.z, __builtin_amdgcn_rcpf(fmaf(e.x, ek.x, 1.f)), a[0]);
            a[1] = fmaf(e.z, __builtin_amdgcn_rcpf(fmaf(e.x, ek.y, 1.f)), a[1]);
            a[2] = fmaf(e.z, __builtin_amdgcn_rcpf(fmaf(e.x, ek.z, 1.f)), a[2]);
            a[3] = fmaf(e.z, __builtin_amdgcn_rcpf(fmaf(e.x, ek.w, 1.f)), a[3]);
            a[4] = fmaf(e.z, __builtin_amdgcn_rcpf(fmaf(e.y, ek.x, 1.f)), a[4]);
            a[5] = fmaf(e.z, __builtin_amdgcn_rcpf(fmaf(e.y, ek.y, 1.f)), a[5]);
            a[6] = fmaf(e.z, __builtin_amdgcn_rcpf(fmaf(e.y, ek.z, 1.f)), a[6]);
            a[7] = fmaf(e.z, __builtin_amdgcn_rcpf(fmaf(e.y, ek.w, 1.f)), a[7]);
        }
    }
    float s0[4], s1[4];
    #pragma unroll
    for (int i = 0; i < 4; i++) {
        bool v = (k0 + i) < vlen;
        s0[i] = v ? a[i] : -1e30f;
        s1[i] = v ? a[4 + i] : -1e30f;
    }

    float m0 = fmaxf(fmaxf(s0[0], s0[1]), fmaxf(s0[2], s0[3]));
    float m1 = fmaxf(fmaxf(s1[0], s1[1]), fmaxf(s1[2], s1[3]));
    #pragma unroll
    for (int off = 32; off > 0; off >>= 1) {
        m0 = fmaxf(m0, __shfl_xor(m0, off, 64));
        m1 = fmaxf(m1, __shfl_xor(m1, off, 64));
    }
    if (lane == 0) { red0[wav] = m0; red1[wav] = m1; }
    __syncthreads();
    m0 = fmaxf(fmaxf(red0[0], red0[1]), fmaxf(red0[2], red0[3]));
    m1 = fmaxf(fmaxf(red1[0], red1[1]), fmaxf(red1[2], red1[3]));

    float e0[4], e1[4], t0 = 0.f, t1 = 0.f;
    #pragma unroll
    for (int i = 0; i < 4; i++) {
        e0[i] = __expf(s0[i] - m0);   // masked -> exactly 0
        e1[i] = __expf(s1[i] - m1);
        t0 += e0[i]; t1 += e1[i];
    }
    #pragma unroll
    for (int off = 32; off > 0; off >>= 1) {
        t0 += __shfl_xor(t0, off, 64);
        t1 += __shfl_xor(t1, off, 64);
    }
    __syncthreads();
    if (lane == 0) { red0[wav] = t0; red1[wav] = t1; }
    __syncthreads();
    float inv0 = 1.0f / (red0[0] + red0[1] + red0[2] + red0[3]);
    float inv1 = 1.0f / (red1[0] + red1[1] + red1[2] + red1[3]);

    float* p0 = p + (size_t)bq0 * KLEN + k0;
    *(float4*)(p0)        = make_float4(e0[0] * inv0, e0[1] * inv0, e0[2] * inv0, e0[3] * inv0);
    *(float4*)(p0 + KLEN) = make_float4(e1[0] * inv1, e1[1] * inv1, e1[2] * inv1, e1[3] * inv1);
}

// ============ attn @ V ============
// Grid 1024 = (16 b XCD-swizzled) x (8 q-tiles of 8) x (8 k-eighths of 128).
// p-tile in LDS [k][q] (reads wave-uniform -> broadcast); wave owns 2 q,
// lanes own d4. Always stores -> poison-safe.
__global__ __launch_bounds__(256) void av_kernel(
    const float* __restrict__ p, const float* __restrict__ values,
    const int* __restrict__ valid_lens, float* __restrict__ part)
{
    __shared__ float pt[128][10];

    int blk = blockIdx.x;
    int xcd = blk & 7, s = blk >> 3;
    int b = ((s >> 6) << 3) | xcd;
    int r = s & 63, qt = r >> 3, kq = r & 7;
    int tid = threadIdx.x, lane = tid & 63, w = tid >> 6;
    int vlen = valid_lens[b];
    int kbeg = kq << 7;
    int kc = vlen - kbeg; kc = kc < 0 ? 0 : (kc > 128 ? 128 : kc);
    int bq0 = b * 64 + qt * 8;

    {   // stage p[8q][128k] -> pt[k][q]
        int q = tid >> 5, k4 = (tid & 31) << 2;
        float4 pv = *(const float4*)(p + (size_t)(bq0 + q) * KLEN + kbeg + k4);
        pt[k4 + 0][q] = pv.x;
        pt[k4 + 1][q] = pv.y;
        pt[k4 + 2][q] = pv.z;
        pt[k4 + 3][q] = pv.w;
    }
    __syncthreads();

    const float* vb = values + ((size_t)b * KLEN + kbeg) * DDIM + (lane << 2);
    float4 a0 = make_float4(0.f, 0.f, 0.f, 0.f);
    float4 a1 = make_float4(0.f, 0.f, 0.f, 0.f);

    int kcc = (kc + 31) & ~31;     // p==0 beyond vlen, V rows always in-bounds
    for (int kt = 0; kt < kcc; kt += 32) {
        #pragma unroll
        for (int k2 = 0; k2 < 32; k2++) {
            int k = kt + k2;
            float2 pp = *(const float2*)(&pt[k][w << 1]);
            float4 v  = *(const float4*)(vb + (size_t)k * DDIM);
            a0.x = fmaf(pp.x, v.x, a0.x); a0.y = fmaf(pp.x, v.y, a0.y);
            a0.z = fmaf(pp.x, v.z, a0.z); a0.w = fmaf(pp.x, v.w, a0.w);
            a1.x = fmaf(pp.y, v.x, a1.x); a1.y = fmaf(pp.y, v.y, a1.y);
            a1.z = fmaf(pp.y, v.z, a1.z); a1.w = fmaf(pp.y, v.w, a1.w);
        }
    }
    float* d0 = part + ((size_t)kq * 1024 + bq0 + (w << 1)) * DDIM + (lane << 2);
    *(float4*)(d0)        = a0;
    *(float4*)(d0 + DDIM) = a1;
}

// ============ sum 8 k-partials ============
__global__ __launch_bounds__(256) void combine_kernel(
    const float* __restrict__ part, float* __restrict__ out)
{
    int i = blockIdx.x * 256 + threadIdx.x;        // 65536 float4 slots
    const float4* p4 = (const float4*)part;
    float4 a = p4[i];
    #pragma unroll
    for (int j = 1; j < 8; j++) {
        float4 v = p4[(size_t)j * 65536 + i];
        a.x += v.x; a.y += v.y; a.z += v.z; a.w += v.w;
    }
    ((float4*)out)[i] = a;
}

extern "C" void kernel_launch(void* const* d_in, const int* in_sizes, int n_in,
                              void* d_out, int out_size, void* d_ws, size_t ws_size,
                              hipStream_t stream) {
    const float* queries    = (const float*)d_in[0]; // [16,64,256]
    const float* keys       = (const float*)d_in[1]; // [16,1024,256]
    const float* values     = (const float*)d_in[2]; // [16,1024,256]
    const int*   valid_lens = (const int*)d_in[3];   // [16]
    const float* W_q        = (const float*)d_in[4]; // [256,128]
    const float* W_k        = (const float*)d_in[5]; // [256,128]
    const float* w_v        = (const float*)d_in[6]; // [128]

    float* Eq   = (float*)d_ws;            // 1024*128     = 512 KB
    float* Ek   = Eq + 131072;             // 16*128*1024  = 8 MB
    float* p    = Ek + 2097152;            // 1024*1024    = 4 MB
    float* part = Ek;                      // alias: Ek dead after score; 8 MB exact

    proj_kernel<<<544, 256, 0, stream>>>(queries, keys, W_q, W_k, Eq, Ek);
    score_kernel<<<512, 256, 0, stream>>>(Eq, Ek, w_v, valid_lens, p);
    av_kernel<<<1024, 256, 0, stream>>>(p, values, valid_lens, part);
    combine_kernel<<<256, 256, 0, stream>>>(part, (float*)d_out);
}

// Round 10
// 178.833 us; speedup vs baseline: 1.0085x; 1.0085x over previous
//
#include <hip/hip_runtime.h>

#define DDIM 256
#define HDIM 128
#define KLEN 1024
#define SCL 2.8853900817779268f   // 2*log2(e): exp2(SCL*x) == e^{2x}
#define WSTR 132                  // wt row stride for 128-d half; mult of 4

// ============ Projection -> Eq/Ek = exp2(SCL * in@W) ============
// Block = 64 rows x 64 h-half, 256 threads (r9 mapping: hg=tid&31 h-pair
// (hg,hg+32), rg=tid>>5 8-row group). W staged in TWO d-halves of 33.8 KB
// (wt[64][132]) -> 4 blocks/CU instead of 2. Grid 544.
__global__ __launch_bounds__(256) void proj_kernel(
    const float* __restrict__ queries, const float* __restrict__ keys,
    const float* __restrict__ W_q, const float* __restrict__ W_k,
    float* __restrict__ Eq, float* __restrict__ Ek)
{
    __shared__ union {
        float w[64 * WSTR];   // 33.8 KB: wt[h][d] = W[dt+d][hbase+h], d in [0,128)
        float t[64][68];      // keys transpose staging (epilogue only)
    } sm;

    int tid = threadIdx.x;
    int hg  = tid & 31;       // h index; owns hg and hg+32
    int rg  = tid >> 5;       // row-group (8 rows)
    int blk = blockIdx.x;

    const float* in; const float* W; int row0, hbase, b = 0, kc0 = 0; bool iskey;
    if (blk < 512) {
        iskey = true;
        int xcd = blk & 7, s = blk >> 3;
        b = ((s >= 32) ? 8 : 0) + xcd;
        int r = s & 31;
        kc0   = (r >> 1) * 64;
        hbase = (r & 1) << 6;
        row0  = b * KLEN + kc0;
        in = keys; W = W_k;
    } else {
        iskey = false;
        int qi = blk - 512;
        row0  = (qi >> 1) * 64;
        hbase = (qi & 1) << 6;
        in = queries; W = W_q;
    }

    const float* r0p = in + (size_t)(row0 + rg * 8) * DDIM;
    float2 acc[8];
    #pragma unroll
    for (int j = 0; j < 8; j++) acc[j] = make_float2(0.f, 0.f);

    for (int dt = 0; dt < DDIM; dt += 128) {
        __syncthreads();   // previous half's reads done
        // stage W[dt..dt+127][hbase..+63] -> wt[h][d] via 4x4 register transpose
        {
            int d4g = tid >> 4;            // 0..15
            int hl  = (tid & 15) << 2;     // 0..60
            #pragma unroll
            for (int i = 0; i < 2; i++) {
                int d = i * 64 + d4g * 4;  // 0..124 local
                const float* wg = W + (size_t)(dt + d) * HDIM + hbase + hl;
                float4 g0 = *(const float4*)(wg);
                float4 g1 = *(const float4*)(wg + HDIM);
                float4 g2 = *(const float4*)(wg + 2 * HDIM);
                float4 g3 = *(const float4*)(wg + 3 * HDIM);
                *(float4*)(&sm.w[(hl + 0) * WSTR + d]) = make_float4(g0.x, g1.x, g2.x, g3.x);
                *(float4*)(&sm.w[(hl + 1) * WSTR + d]) = make_float4(g0.y, g1.y, g2.y, g3.y);
                *(float4*)(&sm.w[(hl + 2) * WSTR + d]) = make_float4(g0.z, g1.z, g2.z, g3.z);
                *(float4*)(&sm.w[(hl + 3) * WSTR + d]) = make_float4(g0.w, g1.w, g2.w, g3.w);
            }
        }
        __syncthreads();

        const float* wp0 = &sm.w[(size_t)hg * WSTR];
        const float* wp1 = &sm.w[(size_t)(hg + 32) * WSTR];
        #pragma unroll 4
        for (int d0 = 0; d0 < 128; d0 += 4) {
            float4 w0 = *(const float4*)(wp0 + d0);
            float4 w1 = *(const float4*)(wp1 + d0);
            #pragma unroll
            for (int j = 0; j < 8; j++) {
                float4 a = *(const float4*)(r0p + (size_t)j * DDIM + dt + d0);
                acc[j].x = fmaf(a.x, w0.x, acc[j].x); acc[j].y = fmaf(a.x, w1.x, acc[j].y);
                acc[j].x = fmaf(a.y, w0.y, acc[j].x); acc[j].y = fmaf(a.y, w1.y, acc[j].y);
                acc[j].x = fmaf(a.z, w0.z, acc[j].x); acc[j].y = fmaf(a.z, w1.z, acc[j].y);
                acc[j].x = fmaf(a.w, w0.w, acc[j].x); acc[j].y = fmaf(a.w, w1.w, acc[j].y);
            }
        }
    }

    if (!iskey) {
        #pragma unroll
        for (int j = 0; j < 8; j++) {
            float* er = Eq + (size_t)(row0 + rg * 8 + j) * HDIM + hbase;
            er[hg]      = __builtin_amdgcn_exp2f(SCL * acc[j].x);
            er[hg + 32] = __builtin_amdgcn_exp2f(SCL * acc[j].y);
        }
    } else {
        __syncthreads();   // done with sm.w
        #pragma unroll
        for (int j = 0; j < 8; j++) {
            int kl = rg * 8 + j;
            sm.t[hg][kl]      = __builtin_amdgcn_exp2f(SCL * acc[j].x);
            sm.t[hg + 32][kl] = __builtin_amdgcn_exp2f(SCL * acc[j].y);
        }
        __syncthreads();
        float* dst = Ek + (size_t)b * HDIM * KLEN + (size_t)hbase * KLEN + kc0;
        #pragma unroll
        for (int ii = 0; ii < 4; ii++) {
            int i2 = tid + 256 * ii;           // 1024 float4 slots: 64 h x 64 k
            int hh = i2 >> 4, c = (i2 & 15) << 2;
            float4 o = make_float4(sm.t[hh][c], sm.t[hh][c + 1],
                                   sm.t[hh][c + 2], sm.t[hh][c + 3]);
            *(float4*)(dst + (size_t)hh * KLEN + c) = o;
        }
    }
}

// ============ Scores + masked softmax ============
// Grid 512 (XCD-swizzled) = (b, q-pair). 512 threads (8 waves -> 16 waves/CU).
// Thread = 2 contiguous k x 2 q: per h 1 coalesced float2 Ek + 1 LDS b128
// broadcast + 4 rcp + 8 fma. Writes fully-normalized p (masked k -> 0).
__global__ __launch_bounds__(512) void score_kernel(
    const float* __restrict__ Eq, const float* __restrict__ Ek,
    const float* __restrict__ w_v, const int* __restrict__ valid_lens,
    float* __restrict__ p)
{
    __shared__ float4 eqw[HDIM];       // (eq0, eq1, -2*wv, 0)
    __shared__ float red0[8], red1[8];

    int tid = threadIdx.x, lane = tid & 63, wav = tid >> 6;
    int blk = blockIdx.x;
    int xcd = blk & 7, s = blk >> 3;
    int b = ((s >= 32) ? 8 : 0) + xcd;
    int qp = s & 31;
    int bq0 = b * 64 + qp * 2;
    int vlen = valid_lens[b];

    if (tid < HDIM)
        eqw[tid] = make_float4(Eq[(size_t)bq0 * HDIM + tid],
                               Eq[(size_t)(bq0 + 1) * HDIM + tid],
                               -2.0f * w_v[tid], 0.f);
    __syncthreads();

    int k0 = tid << 1;
    float a00 = 0.f, a01 = 0.f, a10 = 0.f, a11 = 0.f;
    if (k0 < vlen) {
        const float* ekp = Ek + (size_t)b * HDIM * KLEN + k0;
        #pragma unroll 8
        for (int h = 0; h < HDIM; h++) {
            float2 ek = *(const float2*)(ekp + (size_t)h * KLEN);
            float4 e  = eqw[h];
            a00 = fmaf(e.z, __builtin_amdgcn_rcpf(fmaf(e.x, ek.x, 1.f)), a00);
            a01 = fmaf(e.z, __builtin_amdgcn_rcpf(fmaf(e.x, ek.y, 1.f)), a01);
            a10 = fmaf(e.z, __builtin_amdgcn_rcpf(fmaf(e.y, ek.x, 1.f)), a10);
            a11 = fmaf(e.z, __builtin_amdgcn_rcpf(fmaf(e.y, ek.y, 1.f)), a11);
        }
    }
    float s00 = (k0 < vlen)     ? a00 : -1e30f;
    float s01 = (k0 + 1 < vlen) ? a01 : -1e30f;
    float s10 = (k0 < vlen)     ? a10 : -1e30f;
    float s11 = (k0 + 1 < vlen) ? a11 : -1e30f;

    float m0 = fmaxf(s00, s01), m1 = fmaxf(s10, s11);
    #pragma unroll
    for (int off = 32; off > 0; off >>= 1) {
        m0 = fmaxf(m0, __shfl_xor(m0, off, 64));
        m1 = fmaxf(m1, __shfl_xor(m1, off, 64));
    }
    if (lane == 0) { red0[wav] = m0; red1[wav] = m1; }
    __syncthreads();
    m0 = red0[0]; m1 = red1[0];
    #pragma unroll
    for (int i = 1; i < 8; i++) {
        m0 = fmaxf(m0, red0[i]);
        m1 = fmaxf(m1, red1[i]);
    }

    float e00 = __expf(s00 - m0), e01 = __expf(s01 - m0);   // masked -> exact 0
    float e10 = __expf(s10 - m1), e11 = __expf(s11 - m1);
    float t0 = e00 + e01, t1 = e10 + e11;
    #pragma unroll
    for (int off = 32; off > 0; off >>= 1) {
        t0 += __shfl_xor(t0, off, 64);
        t1 += __shfl_xor(t1, off, 64);
    }
    __syncthreads();
    if (lane == 0) { red0[wav] = t0; red1[wav] = t1; }
    __syncthreads();
    t0 = red0[0]; t1 = red1[0];
    #pragma unroll
    for (int i = 1; i < 8; i++) { t0 += red0[i]; t1 += red1[i]; }
    float inv0 = 1.0f / t0, inv1 = 1.0f / t1;

    float* p0 = p + (size_t)bq0 * KLEN + k0;
    *(float2*)(p0)        = make_float2(e00 * inv0, e01 * inv0);
    *(float2*)(p0 + KLEN) = make_float2(e10 * inv1, e11 * inv1);
}

// ============ attn @ V ============
// Grid 512 = (16 b XCD-swizzled) x (8 q-tiles of 8) x (4 k-quarters of 256).
// 512 threads (8 waves): wave = (q-pair, k-128-half). p-tile [256k][8q] in
// 10 KB LDS (wave-uniform reads -> broadcast). Always stores -> poison-safe.
__global__ __launch_bounds__(512) void av_kernel(
    const float* __restrict__ p, const float* __restrict__ values,
    const int* __restrict__ valid_lens, float* __restrict__ part)
{
    __shared__ float pt[256][10];

    int blk = blockIdx.x;
    int xcd = blk & 7, s = blk >> 3;
    int b = ((s >= 32) ? 8 : 0) + xcd;
    int r = s & 31, qt = r >> 2, kq = r & 3;
    int tid = threadIdx.x, lane = tid & 63, w = tid >> 6;
    int qp = w & 3, kh = w >> 2;
    int vlen = valid_lens[b];
    int kbeg = kq << 8;
    int bq0 = b * 64 + qt * 8;

    {   // stage p[8q][256k] -> pt[k][q]; one float4 per thread
        int q = tid >> 6, k4 = (tid & 63) << 2;
        float4 pv = *(const float4*)(p + (size_t)(bq0 + q) * KLEN + kbeg + k4);
        pt[k4 + 0][q] = pv.x;
        pt[k4 + 1][q] = pv.y;
        pt[k4 + 2][q] = pv.z;
        pt[k4 + 3][q] = pv.w;
    }
    __syncthreads();

    int klo = kh << 7;                       // 0 or 128 within quarter
    int kcw = vlen - (kbeg + klo);
    kcw = kcw < 0 ? 0 : (kcw > 128 ? 128 : kcw);
    int kcc = (kcw + 31) & ~31;              // p==0 beyond vlen -> safe round-up

    const float* vb = values + ((size_t)b * KLEN + kbeg + klo) * DDIM + (lane << 2);
    float4 a0 = make_float4(0.f, 0.f, 0.f, 0.f);
    float4 a1 = make_float4(0.f, 0.f, 0.f, 0.f);

    for (int kt = 0; kt < kcc; kt += 32) {
        #pragma unroll
        for (int k2 = 0; k2 < 32; k2++) {
            int k = kt + k2;
            float2 pp = *(const float2*)(&pt[klo + k][qp << 1]);
            float4 v  = *(const float4*)(vb + (size_t)k * DDIM);
            a0.x = fmaf(pp.x, v.x, a0.x); a0.y = fmaf(pp.x, v.y, a0.y);
            a0.z = fmaf(pp.x, v.z, a0.z); a0.w = fmaf(pp.x, v.w, a0.w);
            a1.x = fmaf(pp.y, v.x, a1.x); a1.y = fmaf(pp.y, v.y, a1.y);
            a1.z = fmaf(pp.y, v.z, a1.z); a1.w = fmaf(pp.y, v.w, a1.w);
        }
    }
    int ks = (kq << 1) + kh;                 // 0..7 k-slice
    float* d0 = part + ((size_t)ks * 1024 + bq0 + (qp << 1)) * DDIM + (lane << 2);
    *(float4*)(d0)        = a0;
    *(float4*)(d0 + DDIM) = a1;
}

// ============ sum 8 k-partials ============
__global__ __launch_bounds__(256) void combine_kernel(
    const float* __restrict__ part, float* __restrict__ out)
{
    int i = blockIdx.x * 256 + threadIdx.x;        // 65536 float4 slots
    const float4* p4 = (const float4*)part;
    float4 a = p4[i];
    #pragma unroll
    for (int j = 1; j < 8; j++) {
        float4 v = p4[(size_t)j * 65536 + i];
        a.x += v.x; a.y += v.y; a.z += v.z; a.w += v.w;
    }
    ((float4*)out)[i] = a;
}

extern "C" void kernel_launch(void* const* d_in, const int* in_sizes, int n_in,
                              void* d_out, int out_size, void* d_ws, size_t ws_size,
                              hipStream_t stream) {
    const float* queries    = (const float*)d_in[0]; // [16,64,256]
    const float* keys       = (const float*)d_in[1]; // [16,1024,256]
    const float* values     = (const float*)d_in[2]; // [16,1024,256]
    const int*   valid_lens = (const int*)d_in[3];   // [16]
    const float* W_q        = (const float*)d_in[4]; // [256,128]
    const float* W_k        = (const float*)d_in[5]; // [256,128]
    const float* w_v        = (const float*)d_in[6]; // [128]

    float* Eq   = (float*)d_ws;            // 1024*128     = 512 KB
    float* Ek   = Eq + 131072;             // 16*128*1024  = 8 MB
    float* p    = Ek + 2097152;            // 1024*1024    = 4 MB
    float* part = Ek;                      // alias: Ek dead after score; 8 MB exact

    proj_kernel<<<544, 256, 0, stream>>>(queries, keys, W_q, W_k, Eq, Ek);
    score_kernel<<<512, 512, 0, stream>>>(Eq, Ek, w_v, valid_lens, p);
    av_kernel<<<512, 512, 0, stream>>>(p, values, valid_lens, part);
    combine_kernel<<<256, 256, 0, stream>>>(part, (float*)d_out);
}